// Round 1
// baseline (512.192 us; speedup 1.0000x reference)
//
#include <hip/hip_runtime.h>

// Problem constants (fixed by setup_inputs)
#define NN    64
#define CIN   64
#define COUT  64
#define KA    3
#define TDIM  256
#define VV    25
#define TTILE 4
#define SLOC  (TTILE*VV)   // 100 spatial positions per block tile
#define NTT   (TDIM/TTILE) // 64 t-tiles
#define CNT_PER_C 409600.f // NN*TDIM*VV elements per channel

// ---------------- Kernel 1: fused 1x1-conv + adjacency contraction ----------
// block = one (n, t-tile of 4). 256 threads = 4 waves.
// Conv: wave w computes o in [k*64 + w*16, +16) over 128 padded s (2 s/lane).
// Adjacency: thread t owns (c = t/4, tl = t%4), full w-row of 25.
__global__ __launch_bounds__(256) void k_conv_adj(
    const float* __restrict__ x, const float* __restrict__ Wc,
    const float* __restrict__ bc, const float* __restrict__ A,
    float* __restrict__ zout)
{
    __shared__ float xs[CIN * SLOC];        // 25.6 KB
    __shared__ float ys[COUT * TTILE * 28]; // 28 KB  (v padded 25->28 for float4)
    __shared__ float As[KA * VV * 28];      // 8.4 KB (w padded 25->28, zeros)

    const int tid = threadIdx.x;
    const int n  = blockIdx.x >> 6;
    const int tt = blockIdx.x & 63;

    const float* xb = x + (size_t)n * CIN * TDIM * VV + (size_t)tt * SLOC;
    for (int i = tid; i < CIN * SLOC; i += 256) {
        int ci = i / SLOC, s = i % SLOC;
        xs[i] = xb[(size_t)ci * (TDIM * VV) + s];
    }
    for (int i = tid; i < KA * VV * 28; i += 256) {
        int kv = i / 28, w = i % 28;
        As[i] = (w < VV) ? A[kv * VV + w] : 0.f;
    }
    __syncthreads();

    const int lane = tid & 63;
    const int wid  = tid >> 6;
    const bool sval = (lane < 50);              // lanes 50..63 are padding
    const int s0 = sval ? 2 * lane : 0;
    const int s1 = s0 + 1;
    const int off0 = (s0 / VV) * 28 + (s0 % VV); // ys layout [o][tl][28]
    const int off1 = (s1 / VV) * 28 + (s1 % VV);

    const int c  = tid >> 2;   // adjacency ownership
    const int tl = tid & 3;

    float z[28];
#pragma unroll
    for (int j = 0; j < 28; ++j) z[j] = 0.f;

    for (int k = 0; k < KA; ++k) {
#pragma unroll
        for (int ch = 0; ch < 2; ++ch) {
            const int og = k * 64 + wid * 16 + ch * 8;  // global o, wave-uniform
            float a0[8], a1[8];
#pragma unroll
            for (int i = 0; i < 8; ++i) { float b = bc[og + i]; a0[i] = b; a1[i] = b; }
#pragma unroll 4
            for (int ci = 0; ci < CIN; ++ci) {
                float2 xv = *(const float2*)&xs[ci * SLOC + s0];
#pragma unroll
                for (int i = 0; i < 8; ++i) {
                    float wv = Wc[(og + i) * CIN + ci];  // wave-uniform -> s_load
                    a0[i] = fmaf(wv, xv.x, a0[i]);
                    a1[i] = fmaf(wv, xv.y, a1[i]);
                }
            }
            if (sval) {
                const int ol = wid * 16 + ch * 8;
#pragma unroll
                for (int i = 0; i < 8; ++i) {
                    ys[(ol + i) * 112 + off0] = a0[i];
                    ys[(ol + i) * 112 + off1] = a1[i];
                }
            }
        }
        __syncthreads();

        // adjacency: z[c,tl,w] += sum_v ys[c,tl,v] * A[k,v,w]
        float yv[28];
#pragma unroll
        for (int j = 0; j < 7; ++j)
            *(float4*)&yv[4 * j] = *(const float4*)&ys[c * 112 + tl * 28 + 4 * j];
#pragma unroll
        for (int v = 0; v < VV; ++v) {
            float yvv = yv[v];
#pragma unroll
            for (int j = 0; j < 7; ++j) {
                float4 a4 = *(const float4*)&As[(k * VV + v) * 28 + 4 * j]; // broadcast
                z[4 * j + 0] = fmaf(yvv, a4.x, z[4 * j + 0]);
                z[4 * j + 1] = fmaf(yvv, a4.y, z[4 * j + 1]);
                z[4 * j + 2] = fmaf(yvv, a4.z, z[4 * j + 2]);
                z[4 * j + 3] = fmaf(yvv, a4.w, z[4 * j + 3]);
            }
        }
        __syncthreads();
    }

    float* orow = zout + ((size_t)(n * COUT + c) * TDIM + (tt * TTILE + tl)) * VV;
#pragma unroll
    for (int w = 0; w < VV; ++w) orow[w] = z[w];
}

// ---------------- Kernel 2: per-channel partial sums over z ----------------
__global__ __launch_bounds__(256) void k_stats(const float* __restrict__ z,
                                               float* __restrict__ part)
{
    const int c = blockIdx.x & 63;
    const int g = blockIdx.x >> 6;   // 0..15, n-range [4g, 4g+4)
    float s1 = 0.f, s2 = 0.f;
    for (int nn = 0; nn < 4; ++nn) {
        const float4* row = (const float4*)(z + (size_t)((g * 4 + nn) * COUT + c) * (TDIM * VV));
        for (int j = threadIdx.x; j < (TDIM * VV) / 4; j += 256) {
            float4 v = row[j];
            s1 += v.x + v.y + v.z + v.w;
            s2 += v.x * v.x + v.y * v.y + v.z * v.z + v.w * v.w;
        }
    }
#pragma unroll
    for (int o = 1; o < 64; o <<= 1) { s1 += __shfl_xor(s1, o); s2 += __shfl_xor(s2, o); }
    __shared__ float r1[4], r2[4];
    if ((threadIdx.x & 63) == 0) { r1[threadIdx.x >> 6] = s1; r2[threadIdx.x >> 6] = s2; }
    __syncthreads();
    if (threadIdx.x == 0) {
        part[blockIdx.x]        = r1[0] + r1[1] + r1[2] + r1[3];
        part[1024 + blockIdx.x] = r2[0] + r2[1] + r2[2] + r2[3];
    }
}

// ---------------- Kernel 3: fold stats + gamma/beta into (a,b) --------------
__global__ void k_bnparams(const float* __restrict__ part, const float* __restrict__ gamma,
                           const float* __restrict__ beta, float* __restrict__ sc)
{
    int c = threadIdx.x;  // 64 threads
    float s1 = 0.f, s2 = 0.f;
    for (int g = 0; g < 16; ++g) { s1 += part[g * 64 + c]; s2 += part[1024 + g * 64 + c]; }
    float mean = s1 * (1.f / CNT_PER_C);
    float var  = s2 * (1.f / CNT_PER_C) - mean * mean;  // biased, matches jnp.var
    float inv  = rsqrtf(var + 1e-5f);
    float a = gamma[c] * inv;
    sc[c]      = a;
    sc[64 + c] = beta[c] - mean * a;
}

// ---------------- Kernel 4: in-place normalize + affine + ReLU --------------
__global__ __launch_bounds__(256) void k_norm(float* __restrict__ z,
                                              const float* __restrict__ sc)
{
    __shared__ float a_s[64], b_s[64];
    if (threadIdx.x < 64) { a_s[threadIdx.x] = sc[threadIdx.x]; b_s[threadIdx.x] = sc[64 + threadIdx.x]; }
    __syncthreads();
    const int total4 = (NN * COUT * TDIM * VV) / 4;  // 1,638,400
    for (int i = blockIdx.x * 256 + threadIdx.x; i < total4; i += gridDim.x * 256) {
        float4 v = ((float4*)z)[i];
        int c = (i / 1600) & 63;   // 1600 float4 per (n,c) slice
        float a = a_s[c], b = b_s[c];
        v.x = fmaxf(fmaf(v.x, a, b), 0.f);
        v.y = fmaxf(fmaf(v.y, a, b), 0.f);
        v.z = fmaxf(fmaf(v.z, a, b), 0.f);
        v.w = fmaxf(fmaf(v.w, a, b), 0.f);
        ((float4*)z)[i] = v;
    }
}

extern "C" void kernel_launch(void* const* d_in, const int* in_sizes, int n_in,
                              void* d_out, int out_size, void* d_ws, size_t ws_size,
                              hipStream_t stream)
{
    const float* x     = (const float*)d_in[0];
    const float* Wc    = (const float*)d_in[1];
    const float* bc    = (const float*)d_in[2];
    const float* A     = (const float*)d_in[3];
    const float* gamma = (const float*)d_in[4];
    const float* beta  = (const float*)d_in[5];
    // d_in[6] = part (scalar 0), unused

    float* out  = (float*)d_out;
    float* part = (float*)d_ws;        // 2048 floats partials
    float* sc   = part + 2048;         // 128 floats (a,b) -- total ws use 8.7 KB

    k_conv_adj<<<NN * NTT, 256, 0, stream>>>(x, Wc, bc, A, out);
    k_stats<<<1024, 256, 0, stream>>>(out, part);
    k_bnparams<<<1, 64, 0, stream>>>(part, gamma, beta, sc);
    k_norm<<<2048, 256, 0, stream>>>(out, sc);
}

// Round 2
// 204.345 us; speedup vs baseline: 2.5065x; 2.5065x over previous
//
#include <hip/hip_runtime.h>
#include <stdint.h>

// Problem constants
#define NN    64
#define CIN   64
#define TDIM  256
#define VV    25
#define KA    3
#define NT    7      // 7 n-tiles of 16 cover SP=112 padded spatial positions
#define YSTRIDE 116  // y LDS row stride (bank-conflict-free for write & read patterns)
#define NBLK  4096   // NN * (TDIM/4)

typedef __attribute__((ext_vector_type(8))) short bf16x8;
typedef __attribute__((ext_vector_type(4))) float f32x4;
typedef __attribute__((ext_vector_type(4))) short short4v;

__device__ __forceinline__ short f2bf(float f) {
    uint32_t u = __builtin_bit_cast(uint32_t, f);
    u += 0x7fffu + ((u >> 16) & 1u);   // round-to-nearest-even
    return (short)(u >> 16);
}

// ---------------- Kernel 1: bf16-MFMA conv + fp32 adjacency + stats partials
// block = (n, t-tile of 4) -> 100 spatial positions (padded 112). 256 thr = 4 waves.
// Conv GEMM per k: M=64 (o), N=112 (s), K=64 (ci). Wave w owns m-tile w.
// Adjacency: thread t owns (c=t/4, tl=t%4), fp32 VALU, 25x25 per k.
__global__ __launch_bounds__(256, 2) void k_conv_adj(
    const float* __restrict__ x, const float* __restrict__ Wc,
    const float* __restrict__ bc, const float* __restrict__ A,
    float* __restrict__ zout, float* __restrict__ part)
{
    __shared__ short xbf[NT * 2 * 64 * 8];   // 14.3 KB, B-fragment-linear bf16
    __shared__ float ylds[64 * YSTRIDE];     // 29.7 KB
    __shared__ float As[KA * VV * 28];       // 8.4 KB (w padded 25->28, zeros)

    const int tid  = threadIdx.x;
    const int n    = blockIdx.x >> 6;
    const int tt   = blockIdx.x & 63;
    const int lane = tid & 63;
    const int wid  = tid >> 6;

    const float* xb = x + (size_t)n * CIN * TDIM * VV + tt * 100;

    // Stage x -> bf16 LDS in exact B-fragment order: frag[(ntile,ks)][lane][j]
    // element (l,j) = x[ci = ks*32 + (l>>4)*8 + j][s = ntile*16 + (l&15)]
    for (int i = tid; i < 1600; i += 256) {        // 16 ci-quads x 100 s
        int q  = i / 100, sl = i - q * 100;
        int ks = q >> 3, lhi = (q >> 1) & 3, half = q & 1;
        int ntile = sl >> 4, lane2 = (sl & 15) | (lhi << 4);
        const float* p = xb + (size_t)(q * 4) * 6400 + sl;
        short4v v;
        v[0] = f2bf(p[0]);
        v[1] = f2bf(p[6400]);
        v[2] = f2bf(p[12800]);
        v[3] = f2bf(p[19200]);
        *(short4v*)&xbf[(((ntile * 2 + ks) * 64 + lane2) << 3) + half * 4] = v;
    }
    for (int i = tid; i < KA * VV * 28; i += 256) {
        int kv = i / 28, w = i - kv * 28;
        As[i] = (w < VV) ? A[kv * VV + w] : 0.f;
    }
    __syncthreads();

    // B-fragments (x) once: conflict-free ds_read_b128
    bf16x8 bx[NT][2];
#pragma unroll
    for (int nt2 = 0; nt2 < NT; ++nt2)
#pragma unroll
        for (int ks = 0; ks < 2; ++ks)
            bx[nt2][ks] = *(const bf16x8*)&xbf[((nt2 * 2 + ks) * 64 + lane) << 3];

    const int c  = tid >> 2;
    const int tl = tid & 3;
    float z[28];
#pragma unroll
    for (int j = 0; j < 28; ++j) z[j] = 0.f;

    const int arow = wid * 16 + (lane & 15);
    const int klo  = (lane >> 4) * 8;

    for (int k = 0; k < KA; ++k) {
        // A-fragments (W) from global, convert fp32->bf16 in regs
        bf16x8 aW[2];
#pragma unroll
        for (int ks = 0; ks < 2; ++ks) {
            const float* wp = Wc + (size_t)(k * 64 + arow) * CIN + ks * 32 + klo;
            float4 w0 = *(const float4*)wp;
            float4 w1 = *(const float4*)(wp + 4);
            bf16x8 a;
            a[0] = f2bf(w0.x); a[1] = f2bf(w0.y); a[2] = f2bf(w0.z); a[3] = f2bf(w0.w);
            a[4] = f2bf(w1.x); a[5] = f2bf(w1.y); a[6] = f2bf(w1.z); a[7] = f2bf(w1.w);
            aW[ks] = a;
        }
        float4 b4 = *(const float4*)&bc[k * 64 + wid * 16 + (lane >> 4) * 4];

        f32x4 acc[NT];
#pragma unroll
        for (int nt2 = 0; nt2 < NT; ++nt2) {
            f32x4 a0 = {b4.x, b4.y, b4.z, b4.w};   // bias per output row
            a0 = __builtin_amdgcn_mfma_f32_16x16x32_bf16(aW[0], bx[nt2][0], a0, 0, 0, 0);
            a0 = __builtin_amdgcn_mfma_f32_16x16x32_bf16(aW[1], bx[nt2][1], a0, 0, 0, 0);
            acc[nt2] = a0;
        }

        if (k) __syncthreads();   // previous adjacency done before overwriting ylds
        // D layout: row=(lane>>4)*4+r (o_local), col=lane&15 (s within n-tile)
#pragma unroll
        for (int nt2 = 0; nt2 < NT; ++nt2)
#pragma unroll
            for (int r = 0; r < 4; ++r)
                ylds[(wid * 16 + (lane >> 4) * 4 + r) * YSTRIDE + nt2 * 16 + (lane & 15)] = acc[nt2][r];
        __syncthreads();

        // adjacency: z[c,tl,w] += sum_v y[c,tl,v] * A[k,v,w]
        float yv[VV];
#pragma unroll
        for (int v = 0; v < VV; ++v) yv[v] = ylds[c * YSTRIDE + tl * VV + v];
#pragma unroll
        for (int v = 0; v < VV; ++v) {
            float yvv = yv[v];
            const float* ap = &As[(k * VV + v) * 28];
#pragma unroll
            for (int j = 0; j < 7; ++j) {
                float4 a4 = *(const float4*)(ap + 4 * j);   // LDS broadcast
                z[4 * j + 0] = fmaf(yvv, a4.x, z[4 * j + 0]);
                z[4 * j + 1] = fmaf(yvv, a4.y, z[4 * j + 1]);
                z[4 * j + 2] = fmaf(yvv, a4.z, z[4 * j + 2]);
                z[4 * j + 3] = fmaf(yvv, a4.w, z[4 * j + 3]);
            }
        }
    }

    float* orow = zout + ((size_t)(n * 64 + c) * TDIM + tt * 4 + tl) * VV;
    float s1 = 0.f, s2 = 0.f;
#pragma unroll
    for (int w = 0; w < VV; ++w) { orow[w] = z[w]; s1 += z[w]; s2 += z[w] * z[w]; }

    if (part) {   // fused BN-stats partials (deterministic, per-block slot)
        s1 += __shfl_xor(s1, 1); s1 += __shfl_xor(s1, 2);
        s2 += __shfl_xor(s2, 1); s2 += __shfl_xor(s2, 2);
        if (tl == 0) {
            part[(size_t)c * NBLK + blockIdx.x]          = s1;
            part[262144 + (size_t)c * NBLK + blockIdx.x] = s2;
        }
    }
}

// ---------------- Kernel 2: reduce partials -> per-channel (a,b) -------------
__global__ __launch_bounds__(256) void k_reduce(
    const float* __restrict__ part, const float* __restrict__ gamma,
    const float* __restrict__ beta, float* __restrict__ sc)
{
    const int c = blockIdx.x;
    const float* p1 = part + (size_t)c * NBLK;
    const float* p2 = part + 262144 + (size_t)c * NBLK;
    float s1 = 0.f, s2 = 0.f;
    for (int i = threadIdx.x; i < NBLK; i += 256) { s1 += p1[i]; s2 += p2[i]; }
#pragma unroll
    for (int o = 1; o < 64; o <<= 1) { s1 += __shfl_xor(s1, o); s2 += __shfl_xor(s2, o); }
    __shared__ float r1[4], r2[4];
    if ((threadIdx.x & 63) == 0) { r1[threadIdx.x >> 6] = s1; r2[threadIdx.x >> 6] = s2; }
    __syncthreads();
    if (threadIdx.x == 0) {
        float t1 = r1[0] + r1[1] + r1[2] + r1[3];
        float t2 = r2[0] + r2[1] + r2[2] + r2[3];
        float mean = t1 * (1.f / 409600.f);
        float var  = t2 * (1.f / 409600.f) - mean * mean;
        float a = gamma[c] * rsqrtf(var + 1e-5f);
        sc[c]      = a;
        sc[64 + c] = beta[c] - mean * a;
    }
}

// ---------------- Fallback stats path (small ws): re-read z -----------------
__global__ __launch_bounds__(256) void k_stats(const float* __restrict__ z,
                                               float* __restrict__ part)
{
    const int c = blockIdx.x & 63;
    const int g = blockIdx.x >> 6;
    float s1 = 0.f, s2 = 0.f;
    for (int nn = 0; nn < 4; ++nn) {
        const float4* row = (const float4*)(z + (size_t)((g * 4 + nn) * 64 + c) * (TDIM * VV));
        for (int j = threadIdx.x; j < (TDIM * VV) / 4; j += 256) {
            float4 v = row[j];
            s1 += v.x + v.y + v.z + v.w;
            s2 += v.x * v.x + v.y * v.y + v.z * v.z + v.w * v.w;
        }
    }
#pragma unroll
    for (int o = 1; o < 64; o <<= 1) { s1 += __shfl_xor(s1, o); s2 += __shfl_xor(s2, o); }
    __shared__ float r1[4], r2[4];
    if ((threadIdx.x & 63) == 0) { r1[threadIdx.x >> 6] = s1; r2[threadIdx.x >> 6] = s2; }
    __syncthreads();
    if (threadIdx.x == 0) {
        part[blockIdx.x]        = r1[0] + r1[1] + r1[2] + r1[3];
        part[1024 + blockIdx.x] = r2[0] + r2[1] + r2[2] + r2[3];
    }
}

__global__ void k_bnparams(const float* __restrict__ part, const float* __restrict__ gamma,
                           const float* __restrict__ beta, float* __restrict__ sc)
{
    int c = threadIdx.x;
    float s1 = 0.f, s2 = 0.f;
    for (int g = 0; g < 16; ++g) { s1 += part[g * 64 + c]; s2 += part[1024 + g * 64 + c]; }
    float mean = s1 * (1.f / 409600.f);
    float var  = s2 * (1.f / 409600.f) - mean * mean;
    float a = gamma[c] * rsqrtf(var + 1e-5f);
    sc[c]      = a;
    sc[64 + c] = beta[c] - mean * a;
}

// ---------------- Kernel 3: in-place normalize + affine + ReLU --------------
__global__ __launch_bounds__(256) void k_norm(float* __restrict__ z,
                                              const float* __restrict__ sc)
{
    __shared__ float a_s[64], b_s[64];
    if (threadIdx.x < 64) { a_s[threadIdx.x] = sc[threadIdx.x]; b_s[threadIdx.x] = sc[64 + threadIdx.x]; }
    __syncthreads();
    const int total4 = (NN * 64 * TDIM * VV) / 4;
    for (int i = blockIdx.x * 256 + threadIdx.x; i < total4; i += gridDim.x * 256) {
        float4 v = ((float4*)z)[i];
        int c = (i / 1600) & 63;
        float a = a_s[c], b = b_s[c];
        v.x = fmaxf(fmaf(v.x, a, b), 0.f);
        v.y = fmaxf(fmaf(v.y, a, b), 0.f);
        v.z = fmaxf(fmaf(v.z, a, b), 0.f);
        v.w = fmaxf(fmaf(v.w, a, b), 0.f);
        ((float4*)z)[i] = v;
    }
}

extern "C" void kernel_launch(void* const* d_in, const int* in_sizes, int n_in,
                              void* d_out, int out_size, void* d_ws, size_t ws_size,
                              hipStream_t stream)
{
    const float* x     = (const float*)d_in[0];
    const float* Wc    = (const float*)d_in[1];
    const float* bc    = (const float*)d_in[2];
    const float* A     = (const float*)d_in[3];
    const float* gamma = (const float*)d_in[4];
    const float* beta  = (const float*)d_in[5];

    float* out = (float*)d_out;
    const size_t need = (size_t)(2 * 64 * NBLK + 128) * sizeof(float);  // ~2.1 MB

    if (ws_size >= need) {
        float* part = (float*)d_ws;
        float* sc   = part + 2 * 64 * NBLK;
        k_conv_adj<<<NBLK, 256, 0, stream>>>(x, Wc, bc, A, out, part);
        k_reduce<<<64, 256, 0, stream>>>(part, gamma, beta, sc);
        k_norm<<<2048, 256, 0, stream>>>(out, sc);
    } else {
        float* part = (float*)d_ws;
        float* sc   = part + 2048;
        k_conv_adj<<<NBLK, 256, 0, stream>>>(x, Wc, bc, A, out, nullptr);
        k_stats<<<1024, 256, 0, stream>>>(out, part);
        k_bnparams<<<1, 64, 0, stream>>>(part, gamma, beta, sc);
        k_norm<<<2048, 256, 0, stream>>>(out, sc);
    }
}

// Round 3
// 143.481 us; speedup vs baseline: 3.5698x; 1.4242x over previous
//
#include <hip/hip_runtime.h>
#include <stdint.h>

// Problem constants
#define NN    64
#define CIN   64
#define TDIM  256
#define VV    25
#define KA    3
#define NT7   7      // 7 n-tiles of 16 cover 112 padded spatial positions
#define NBLK  4096   // NN * (TDIM/4)

typedef __attribute__((ext_vector_type(8))) short bf16x8;
typedef __attribute__((ext_vector_type(4))) float f32x4;
typedef __attribute__((ext_vector_type(4))) short short4v;

__device__ __forceinline__ short f2bf(float f) {
    uint32_t u = __builtin_bit_cast(uint32_t, f);
    u += 0x7fffu + ((u >> 16) & 1u);   // round-to-nearest-even
    return (short)(u >> 16);
}
// y2 row address (in shorts): stride 40 + 8-short skew per 16-row block
// (skew decorrelates the 4 lane-groups' write banks; keeps 16B alignment)
__device__ __forceinline__ int y2idx(int m) { return m * 40 + ((m >> 4) << 3); }

// ---------------- Kernel 1: bf16-MFMA conv + bf16-MFMA adjacency + stats ----
// block = (n, t-tile of 4) -> 100 spatial positions. 256 thr = 4 waves.
// Conv GEMM per k: M=64 (o), N=112 (s), K=64 (ci)   -> 14 MFMA/wave
// Adj  GEMM per k: M=256 (c,tl), N=32 (w pad), K=32 (v pad) -> 8 MFMA/wave
__global__ __launch_bounds__(256, 4) void k_conv_adj(
    const float* __restrict__ x, const float* __restrict__ Wc,
    const float* __restrict__ bc, const float* __restrict__ A,
    float* __restrict__ zout, float* __restrict__ part)
{
    // y2: 256 rows * 40 shorts + skew (10368 shorts, 20.7KB). xbf (7168 shorts)
    // aliases y2's space: xbf is dead after the register preload of B-frags.
    // At: 3*32*40 shorts (7.7KB). Total 28.4KB -> 4+ blocks/CU.
    __shared__ __align__(16) short smem[10368 + 3840];
    short* y2  = smem;
    short* xbf = smem;
    short* At  = smem + 10368;

    const int tid  = threadIdx.x;
    const int n    = blockIdx.x >> 6;
    const int tt   = blockIdx.x & 63;
    const int lane = tid & 63;
    const int wid  = tid >> 6;
    const int cl   = lane & 15;
    const int g    = lane >> 4;

    // ---- stage x -> bf16 LDS in exact B-fragment order ----
    // frag element (l,j) = x[ci = ks*32 + (l>>4)*8 + j][s = ntile*16 + (l&15)]
    const float* xb = x + (size_t)n * CIN * TDIM * VV + tt * 100;
    for (int i = tid; i < 1600; i += 256) {
        int q = i / 100, sl = i - q * 100;
        int ks = q >> 3, lhi = (q >> 1) & 3, half = q & 1;
        int ntile = sl >> 4, lane2 = (sl & 15) | (lhi << 4);
        const float* p = xb + (size_t)(q * 4) * 6400 + sl;
        short4v v;
        v[0] = f2bf(p[0]);
        v[1] = f2bf(p[6400]);
        v[2] = f2bf(p[12800]);
        v[3] = f2bf(p[19200]);
        *(short4v*)&xbf[(((ntile * 2 + ks) * 64 + lane2) << 3) + half * 4] = v;
    }
    // ---- stage A^T as bf16 B-fragments: At[k][w(pad32)][v(stride40)] ----
    // zero-padded: w>=25 rows -> D cols w>=25 are exact 0; v>=25 -> K-pad 0.
    for (int i = tid; i < 3 * 32 * 40; i += 256) {
        int k3 = i / 1280, r = i - k3 * 1280;
        int w = r / 40, v = r - w * 40;
        float a = (w < VV && v < VV) ? A[(k3 * VV + v) * VV + w] : 0.f;
        At[i] = f2bf(a);
    }
    __syncthreads();

    // ---- preload conv B-frags (x) into registers; xbf dead afterwards ----
    bf16x8 bx[NT7][2];
#pragma unroll
    for (int nt = 0; nt < NT7; ++nt)
#pragma unroll
        for (int ks = 0; ks < 2; ++ks)
            bx[nt][ks] = *(const bf16x8*)&xbf[((nt * 2 + ks) * 64 + lane) << 3];
    __syncthreads();   // all waves done reading xbf; y2 space is now free

    // zero y2 K-pad columns v=25..31 (read by adjacency A-frags, never written)
    for (int i = tid; i < 256 * 7; i += 256) {
        int m = i / 7, v = 25 + (i - m * 7);
        y2[y2idx(m) + v] = 0;
    }

    f32x4 zacc[4][2];
#pragma unroll
    for (int mt = 0; mt < 4; ++mt)
#pragma unroll
        for (int nt = 0; nt < 2; ++nt)
            zacc[mt][nt] = (f32x4){0.f, 0.f, 0.f, 0.f};

    const int arow = wid * 16 + cl;
    const int klo  = g * 8;

    for (int k = 0; k < KA; ++k) {
        // conv A-frags (W) straight from global (L2-resident), fp32->bf16
        bf16x8 aW[2];
#pragma unroll
        for (int ks = 0; ks < 2; ++ks) {
            const float* wp = Wc + (size_t)(k * 64 + arow) * CIN + ks * 32 + klo;
            float4 w0 = *(const float4*)wp;
            float4 w1 = *(const float4*)(wp + 4);
            bf16x8 a;
            a[0] = f2bf(w0.x); a[1] = f2bf(w0.y); a[2] = f2bf(w0.z); a[3] = f2bf(w0.w);
            a[4] = f2bf(w1.x); a[5] = f2bf(w1.y); a[6] = f2bf(w1.z); a[7] = f2bf(w1.w);
            aW[ks] = a;
        }
        float4 b4 = *(const float4*)&bc[k * 64 + wid * 16 + g * 4];

        f32x4 acc[NT7];
#pragma unroll
        for (int nt = 0; nt < NT7; ++nt) {
            f32x4 a0 = {b4.x, b4.y, b4.z, b4.w};   // bias folded pre-adjacency
            a0 = __builtin_amdgcn_mfma_f32_16x16x32_bf16(aW[0], bx[nt][0], a0, 0, 0, 0);
            a0 = __builtin_amdgcn_mfma_f32_16x16x32_bf16(aW[1], bx[nt][1], a0, 0, 0, 0);
            acc[nt] = a0;
        }

        if (k) __syncthreads();   // previous adjacency reads done before overwrite

        // conv D -> y2 bf16 A-fragment layout: row m=(o*4+tl), col v
        // D: o = wid*16 + g*4 + r, s = nt*16 + cl; tl=s/25, v=s%25
#pragma unroll
        for (int nt = 0; nt < NT7; ++nt) {
            int s = nt * 16 + cl;
            if (s < 100) {
                int tl = s / 25, v = s - tl * 25;
                // m = wid*64 + g*16 + r*4 + tl; m>>4 const over r -> linear +160/r
                int base = (wid * 64 + g * 16 + tl) * 40 + (wid * 4 + g) * 8 + v;
#pragma unroll
                for (int r = 0; r < 4; ++r)
                    y2[base + r * 160] = f2bf(acc[nt][r]);
            }
        }
        __syncthreads();

        // adjacency MFMA: z[m][w] += y[m][v] * At[w][v]^T
        bf16x8 atf[2];
#pragma unroll
        for (int nt = 0; nt < 2; ++nt)
            atf[nt] = *(const bf16x8*)&At[(k * 32 + nt * 16 + cl) * 40 + g * 8];
#pragma unroll
        for (int mt = 0; mt < 4; ++mt) {
            int gmt = wid * 4 + mt;
            bf16x8 yf = *(const bf16x8*)&y2[(gmt * 16 + cl) * 40 + gmt * 8 + g * 8];
            zacc[mt][0] = __builtin_amdgcn_mfma_f32_16x16x32_bf16(yf, atf[0], zacc[mt][0], 0, 0, 0);
            zacc[mt][1] = __builtin_amdgcn_mfma_f32_16x16x32_bf16(yf, atf[1], zacc[mt][1], 0, 0, 0);
        }
    }

    // ---- epilogue: store z + fused per-channel BN partials ----
    // D: row m = gmt*16 + g*4 + r  (c=m>>2, tl=m&3), col w = nt*16 + cl
    float* zb = zout + (size_t)n * 64 * TDIM * VV;
#pragma unroll
    for (int mt = 0; mt < 4; ++mt) {
        int gmt = wid * 4 + mt;
        float s1 = 0.f, s2 = 0.f;
#pragma unroll
        for (int nt = 0; nt < 2; ++nt) {
            int w = nt * 16 + cl;
#pragma unroll
            for (int r = 0; r < 4; ++r) {
                float val = zacc[mt][nt][r];
                s1 += val; s2 += val * val;   // pad cols are exact 0 -> safe
                if (w < VV) {
                    int m = gmt * 16 + g * 4 + r;
                    zb[(size_t)(m >> 2) * 6400 + (tt * 4 + (m & 3)) * VV + w] = val;
                }
            }
        }
        s1 += __shfl_xor(s1, 1); s2 += __shfl_xor(s2, 1);
        s1 += __shfl_xor(s1, 2); s2 += __shfl_xor(s2, 2);
        s1 += __shfl_xor(s1, 4); s2 += __shfl_xor(s2, 4);
        s1 += __shfl_xor(s1, 8); s2 += __shfl_xor(s2, 8);
        if (part != nullptr && cl == 0) {
            int c = gmt * 4 + g;
            part[(size_t)c * NBLK + blockIdx.x]          = s1;
            part[262144 + (size_t)c * NBLK + blockIdx.x] = s2;
        }
    }
}

// ---------------- Kernel 2: reduce partials -> per-channel (a,b) -------------
__global__ __launch_bounds__(256) void k_reduce(
    const float* __restrict__ part, const float* __restrict__ gamma,
    const float* __restrict__ beta, float* __restrict__ sc)
{
    const int c = blockIdx.x;
    const float* p1 = part + (size_t)c * NBLK;
    const float* p2 = part + 262144 + (size_t)c * NBLK;
    float s1 = 0.f, s2 = 0.f;
    for (int i = threadIdx.x; i < NBLK; i += 256) { s1 += p1[i]; s2 += p2[i]; }
#pragma unroll
    for (int o = 1; o < 64; o <<= 1) { s1 += __shfl_xor(s1, o); s2 += __shfl_xor(s2, o); }
    __shared__ float r1[4], r2[4];
    if ((threadIdx.x & 63) == 0) { r1[threadIdx.x >> 6] = s1; r2[threadIdx.x >> 6] = s2; }
    __syncthreads();
    if (threadIdx.x == 0) {
        float t1 = r1[0] + r1[1] + r1[2] + r1[3];
        float t2 = r2[0] + r2[1] + r2[2] + r2[3];
        float mean = t1 * (1.f / 409600.f);
        float var  = t2 * (1.f / 409600.f) - mean * mean;
        float a = gamma[c] * rsqrtf(var + 1e-5f);
        sc[c]      = a;
        sc[64 + c] = beta[c] - mean * a;
    }
}

// ---------------- Fallback stats path (small ws): re-read z -----------------
__global__ __launch_bounds__(256) void k_stats(const float* __restrict__ z,
                                               float* __restrict__ part)
{
    const int c = blockIdx.x & 63;
    const int gg = blockIdx.x >> 6;
    float s1 = 0.f, s2 = 0.f;
    for (int nn = 0; nn < 4; ++nn) {
        const float4* row = (const float4*)(z + (size_t)((gg * 4 + nn) * 64 + c) * (TDIM * VV));
        for (int j = threadIdx.x; j < (TDIM * VV) / 4; j += 256) {
            float4 v = row[j];
            s1 += v.x + v.y + v.z + v.w;
            s2 += v.x * v.x + v.y * v.y + v.z * v.z + v.w * v.w;
        }
    }
#pragma unroll
    for (int o = 1; o < 64; o <<= 1) { s1 += __shfl_xor(s1, o); s2 += __shfl_xor(s2, o); }
    __shared__ float r1[4], r2[4];
    if ((threadIdx.x & 63) == 0) { r1[threadIdx.x >> 6] = s1; r2[threadIdx.x >> 6] = s2; }
    __syncthreads();
    if (threadIdx.x == 0) {
        part[blockIdx.x]        = r1[0] + r1[1] + r1[2] + r1[3];
        part[1024 + blockIdx.x] = r2[0] + r2[1] + r2[2] + r2[3];
    }
}

__global__ void k_bnparams(const float* __restrict__ part, const float* __restrict__ gamma,
                           const float* __restrict__ beta, float* __restrict__ sc)
{
    int c = threadIdx.x;
    float s1 = 0.f, s2 = 0.f;
    for (int gg = 0; gg < 16; ++gg) { s1 += part[gg * 64 + c]; s2 += part[1024 + gg * 64 + c]; }
    float mean = s1 * (1.f / 409600.f);
    float var  = s2 * (1.f / 409600.f) - mean * mean;
    float a = gamma[c] * rsqrtf(var + 1e-5f);
    sc[c]      = a;
    sc[64 + c] = beta[c] - mean * a;
}

// ---------------- Kernel 3: in-place normalize + affine + ReLU --------------
__global__ __launch_bounds__(256) void k_norm(float* __restrict__ z,
                                              const float* __restrict__ sc)
{
    __shared__ float a_s[64], b_s[64];
    if (threadIdx.x < 64) { a_s[threadIdx.x] = sc[threadIdx.x]; b_s[threadIdx.x] = sc[64 + threadIdx.x]; }
    __syncthreads();
    const int total4 = (NN * 64 * TDIM * VV) / 4;
    for (int i = blockIdx.x * 256 + threadIdx.x; i < total4; i += gridDim.x * 256) {
        float4 v = ((float4*)z)[i];
        int c = (i / 1600) & 63;
        float a = a_s[c], b = b_s[c];
        v.x = fmaxf(fmaf(v.x, a, b), 0.f);
        v.y = fmaxf(fmaf(v.y, a, b), 0.f);
        v.z = fmaxf(fmaf(v.z, a, b), 0.f);
        v.w = fmaxf(fmaf(v.w, a, b), 0.f);
        ((float4*)z)[i] = v;
    }
}

extern "C" void kernel_launch(void* const* d_in, const int* in_sizes, int n_in,
                              void* d_out, int out_size, void* d_ws, size_t ws_size,
                              hipStream_t stream)
{
    const float* x     = (const float*)d_in[0];
    const float* Wc    = (const float*)d_in[1];
    const float* bc    = (const float*)d_in[2];
    const float* A     = (const float*)d_in[3];
    const float* gamma = (const float*)d_in[4];
    const float* beta  = (const float*)d_in[5];

    float* out = (float*)d_out;
    const size_t need = (size_t)(2 * 64 * NBLK + 128) * sizeof(float);  // ~2.1 MB

    if (ws_size >= need) {
        float* part = (float*)d_ws;
        float* sc   = part + 2 * 64 * NBLK;
        k_conv_adj<<<NBLK, 256, 0, stream>>>(x, Wc, bc, A, out, part);
        k_reduce<<<64, 256, 0, stream>>>(part, gamma, beta, sc);
        k_norm<<<2048, 256, 0, stream>>>(out, sc);
    } else {
        float* part = (float*)d_ws;
        float* sc   = part + 2048;
        k_conv_adj<<<NBLK, 256, 0, stream>>>(x, Wc, bc, A, out, nullptr);
        k_stats<<<1024, 256, 0, stream>>>(out, part);
        k_bnparams<<<1, 64, 0, stream>>>(part, gamma, beta, sc);
        k_norm<<<2048, 256, 0, stream>>>(out, sc);
    }
}

// Round 4
// 124.717 us; speedup vs baseline: 4.1068x; 1.1504x over previous
//
#include <hip/hip_runtime.h>
#include <stdint.h>

// Problem constants
#define NN    64
#define CIN   64
#define TDIM  256
#define VV    25
#define KA    3
#define NT7   7      // 7 n-tiles of 16 cover 112 padded spatial positions
#define NBLK  4096   // NN * (TDIM/4)
#define ZELEMS 26214400  // 64*64*256*25

typedef __attribute__((ext_vector_type(8))) short bf16x8;
typedef __attribute__((ext_vector_type(8))) short short8;
typedef __attribute__((ext_vector_type(4))) float f32x4;
typedef __attribute__((ext_vector_type(4))) short short4v;

__device__ __forceinline__ short f2bf(float f) {
    uint32_t u = __builtin_bit_cast(uint32_t, f);
    u += 0x7fffu + ((u >> 16) & 1u);   // round-to-nearest-even
    return (short)(u >> 16);
}
__device__ __forceinline__ float bf2f(short s) {
    uint32_t u = ((uint32_t)(uint16_t)s) << 16;
    return __builtin_bit_cast(float, u);
}

// ---------------- Kernel 1: bf16-MFMA conv + bf16-MFMA adjacency + stats ----
// block = (n, t-tile of 4) -> 100 spatial positions. 256 thr = 4 waves.
// KEY: y-exchange between conv and adjacency is INTRA-WAVE (wave w's conv
// channels o in [16w,16w+16) are exactly its adjacency rows m in [64w,64w+64)),
// so the k-loop has NO barriers; only 2 staging barriers per block.
// MODE 0: z -> zout fp32.  MODE 1: z -> zbf bf16 (stats on rounded values).
template<int MODE>
__global__ __launch_bounds__(256, 4) void k_conv_adj(
    const float* __restrict__ x, const float* __restrict__ Wc,
    const float* __restrict__ bc, const float* __restrict__ A,
    float* __restrict__ zout, unsigned short* __restrict__ zbf,
    float* __restrict__ part)
{
    // y2: 4 per-wave regions of 2688 shorts (64 rows * 40 + skew); xbf (7168
    // shorts) aliases y2 (dead after register preload). At: 3*32*40 shorts.
    __shared__ __align__(16) short smem[10752 + 3840];   // 29.2 KB
    short* y2  = smem;
    short* xbf = smem;
    short* At  = smem + 10752;

    const int tid  = threadIdx.x;
    const int n    = blockIdx.x >> 6;
    const int tt   = blockIdx.x & 63;
    const int lane = tid & 63;
    const int wid  = tid >> 6;
    const int cl   = lane & 15;
    const int g    = lane >> 4;

    // ---- stage x -> bf16 LDS in exact B-fragment order ----
    const float* xb = x + (size_t)n * CIN * TDIM * VV + tt * 100;
    for (int i = tid; i < 1600; i += 256) {
        int q = i / 100, sl = i - q * 100;
        int ks = q >> 3, lhi = (q >> 1) & 3, half = q & 1;
        int ntile = sl >> 4, lane2 = (sl & 15) | (lhi << 4);
        const float* p = xb + (size_t)(q * 4) * 6400 + sl;
        short4v v;
        v[0] = f2bf(p[0]);
        v[1] = f2bf(p[6400]);
        v[2] = f2bf(p[12800]);
        v[3] = f2bf(p[19200]);
        *(short4v*)&xbf[(((ntile * 2 + ks) * 64 + lane2) << 3) + half * 4] = v;
    }
    // ---- stage A^T bf16 B-fragments: At[k][w(pad32)][v(stride40)], zero-pad --
    for (int i = tid; i < 3 * 32 * 40; i += 256) {
        int k3 = i / 1280, r = i - k3 * 1280;
        int w = r / 40, v = r - w * 40;
        float a = (w < VV && v < VV) ? A[(k3 * VV + v) * VV + w] : 0.f;
        At[i] = f2bf(a);
    }
    __syncthreads();

    // ---- preload conv B-frags (x) into registers; xbf dead afterwards ----
    bf16x8 bx[NT7][2];
#pragma unroll
    for (int nt = 0; nt < NT7; ++nt)
#pragma unroll
        for (int ks = 0; ks < 2; ++ks)
            bx[nt][ks] = *(const bf16x8*)&xbf[((nt * 2 + ks) * 64 + lane) << 3];
    __syncthreads();   // all waves done with xbf; y2 space free

    // ---- zero own region's v-pads (wave-local, no barrier needed) ----
    const int ybase = wid * 2688;
    for (int i = lane; i < 448; i += 64) {
        int m = i / 7, v = 25 + (i - m * 7);
        y2[ybase + m * 40 + ((m >> 4) << 3) + v] = 0;
    }

    f32x4 zacc[4][2];
#pragma unroll
    for (int mt = 0; mt < 4; ++mt)
#pragma unroll
        for (int ntw = 0; ntw < 2; ++ntw)
            zacc[mt][ntw] = (f32x4){0.f, 0.f, 0.f, 0.f};

    const int arow = wid * 16 + cl;
    const int klo  = g * 8;

    for (int k = 0; k < KA; ++k) {
        // conv A-frags (W) from global (L2-resident), fp32->bf16
        bf16x8 aW[2];
#pragma unroll
        for (int ks = 0; ks < 2; ++ks) {
            const float* wp = Wc + (size_t)(k * 64 + arow) * CIN + ks * 32 + klo;
            float4 w0 = *(const float4*)wp;
            float4 w1 = *(const float4*)(wp + 4);
            bf16x8 a;
            a[0] = f2bf(w0.x); a[1] = f2bf(w0.y); a[2] = f2bf(w0.z); a[3] = f2bf(w0.w);
            a[4] = f2bf(w1.x); a[5] = f2bf(w1.y); a[6] = f2bf(w1.z); a[7] = f2bf(w1.w);
            aW[ks] = a;
        }
        float4 b4 = *(const float4*)&bc[k * 64 + wid * 16 + g * 4];

        // conv MFMA per n-tile; write D straight to own y2 region (bf16).
        // D: o_rel = g*4+r, s = nt*16+cl -> m_local = g*16 + r*4 + tl, col v
#pragma unroll
        for (int nt = 0; nt < NT7; ++nt) {
            f32x4 acc = {b4.x, b4.y, b4.z, b4.w};   // bias folded pre-adjacency
            acc = __builtin_amdgcn_mfma_f32_16x16x32_bf16(aW[0], bx[nt][0], acc, 0, 0, 0);
            acc = __builtin_amdgcn_mfma_f32_16x16x32_bf16(aW[1], bx[nt][1], acc, 0, 0, 0);
            int s = nt * 16 + cl;
            if (s < 100) {
                int tl = s / 25, v = s - tl * 25;
                int base = ybase + (g * 16 + tl) * 40 + g * 8 + v;
#pragma unroll
                for (int r = 0; r < 4; ++r)
                    y2[base + r * 160] = f2bf(acc[r]);
            }
        }
        // adjacency MFMA on own y2 rows (intra-wave; lgkmcnt ordering suffices)
        bf16x8 atf0 = *(const bf16x8*)&At[(k * 32 + cl) * 40 + g * 8];
        bf16x8 atf1 = *(const bf16x8*)&At[(k * 32 + 16 + cl) * 40 + g * 8];
#pragma unroll
        for (int mt = 0; mt < 4; ++mt) {
            bf16x8 yf = *(const bf16x8*)&y2[ybase + (mt * 16 + cl) * 40 + mt * 8 + g * 8];
            zacc[mt][0] = __builtin_amdgcn_mfma_f32_16x16x32_bf16(yf, atf0, zacc[mt][0], 0, 0, 0);
            zacc[mt][1] = __builtin_amdgcn_mfma_f32_16x16x32_bf16(yf, atf1, zacc[mt][1], 0, 0, 0);
        }
    }

    // ---- epilogue: store z + fused per-channel BN partials ----
    // D: m = wid*64 + mt*16 + g*4 + r -> c = wid*16 + mt*4 + g, tl = r
    float*          zb   = zout ? zout + (size_t)n * 64 * TDIM * VV : nullptr;
    unsigned short* zb16 = zbf  ? zbf  + (size_t)n * 64 * TDIM * VV : nullptr;
#pragma unroll
    for (int mt = 0; mt < 4; ++mt) {
        const int c = wid * 16 + mt * 4 + g;
        float s1 = 0.f, s2 = 0.f;
#pragma unroll
        for (int ntw = 0; ntw < 2; ++ntw) {
            int w = ntw * 16 + cl;
#pragma unroll
            for (int r = 0; r < 4; ++r) {
                float val = zacc[mt][ntw][r];
                if (MODE == 1) {
                    short b = f2bf(val);
                    val = bf2f(b);          // stats on rounded values (consistent)
                    if (w < VV)
                        zb16[(size_t)c * 6400 + (tt * 4 + r) * VV + w] = (unsigned short)b;
                } else {
                    if (w < VV)
                        zb[(size_t)c * 6400 + (tt * 4 + r) * VV + w] = val;
                }
                s1 += val; s2 += val * val;   // pad cols are exact 0 -> safe
            }
        }
        s1 += __shfl_xor(s1, 1); s2 += __shfl_xor(s2, 1);
        s1 += __shfl_xor(s1, 2); s2 += __shfl_xor(s2, 2);
        s1 += __shfl_xor(s1, 4); s2 += __shfl_xor(s2, 4);
        s1 += __shfl_xor(s1, 8); s2 += __shfl_xor(s2, 8);
        if (part != nullptr && cl == 0) {
            part[(size_t)c * NBLK + blockIdx.x]          = s1;
            part[262144 + (size_t)c * NBLK + blockIdx.x] = s2;
        }
    }
}

// ---------------- Kernel 2: reduce partials -> per-channel (a,b) -------------
__global__ __launch_bounds__(256) void k_reduce(
    const float* __restrict__ part, const float* __restrict__ gamma,
    const float* __restrict__ beta, float* __restrict__ sc)
{
    const int c = blockIdx.x;
    const float* p1 = part + (size_t)c * NBLK;
    const float* p2 = part + 262144 + (size_t)c * NBLK;
    float s1 = 0.f, s2 = 0.f;
    for (int i = threadIdx.x; i < NBLK; i += 256) { s1 += p1[i]; s2 += p2[i]; }
#pragma unroll
    for (int o = 1; o < 64; o <<= 1) { s1 += __shfl_xor(s1, o); s2 += __shfl_xor(s2, o); }
    __shared__ float r1[4], r2[4];
    if ((threadIdx.x & 63) == 0) { r1[threadIdx.x >> 6] = s1; r2[threadIdx.x >> 6] = s2; }
    __syncthreads();
    if (threadIdx.x == 0) {
        float t1 = r1[0] + r1[1] + r1[2] + r1[3];
        float t2 = r2[0] + r2[1] + r2[2] + r2[3];
        float mean = t1 * (1.f / 409600.f);
        float var  = t2 * (1.f / 409600.f) - mean * mean;
        float a = gamma[c] * rsqrtf(var + 1e-5f);
        sc[c]      = a;
        sc[64 + c] = beta[c] - mean * a;
    }
}

// ---------------- Fallback stats path (tiny ws): re-read fp32 z -------------
__global__ __launch_bounds__(256) void k_stats(const float* __restrict__ z,
                                               float* __restrict__ part)
{
    const int c = blockIdx.x & 63;
    const int gg = blockIdx.x >> 6;
    float s1 = 0.f, s2 = 0.f;
    for (int nn = 0; nn < 4; ++nn) {
        const float4* row = (const float4*)(z + (size_t)((gg * 4 + nn) * 64 + c) * (TDIM * VV));
        for (int j = threadIdx.x; j < (TDIM * VV) / 4; j += 256) {
            float4 v = row[j];
            s1 += v.x + v.y + v.z + v.w;
            s2 += v.x * v.x + v.y * v.y + v.z * v.z + v.w * v.w;
        }
    }
#pragma unroll
    for (int o = 1; o < 64; o <<= 1) { s1 += __shfl_xor(s1, o); s2 += __shfl_xor(s2, o); }
    __shared__ float r1[4], r2[4];
    if ((threadIdx.x & 63) == 0) { r1[threadIdx.x >> 6] = s1; r2[threadIdx.x >> 6] = s2; }
    __syncthreads();
    if (threadIdx.x == 0) {
        part[blockIdx.x]        = r1[0] + r1[1] + r1[2] + r1[3];
        part[1024 + blockIdx.x] = r2[0] + r2[1] + r2[2] + r2[3];
    }
}

__global__ void k_bnparams(const float* __restrict__ part, const float* __restrict__ gamma,
                           const float* __restrict__ beta, float* __restrict__ sc)
{
    int c = threadIdx.x;
    float s1 = 0.f, s2 = 0.f;
    for (int gg = 0; gg < 16; ++gg) { s1 += part[gg * 64 + c]; s2 += part[1024 + gg * 64 + c]; }
    float mean = s1 * (1.f / 409600.f);
    float var  = s2 * (1.f / 409600.f) - mean * mean;
    float a = gamma[c] * rsqrtf(var + 1e-5f);
    sc[c]      = a;
    sc[64 + c] = beta[c] - mean * a;
}

// ---------------- Kernel 3a: in-place fp32 normalize + affine + ReLU --------
__global__ __launch_bounds__(256) void k_norm(float* __restrict__ z,
                                              const float* __restrict__ sc)
{
    __shared__ float a_s[64], b_s[64];
    if (threadIdx.x < 64) { a_s[threadIdx.x] = sc[threadIdx.x]; b_s[threadIdx.x] = sc[64 + threadIdx.x]; }
    __syncthreads();
    const int total4 = ZELEMS / 4;
    for (int i = blockIdx.x * 256 + threadIdx.x; i < total4; i += gridDim.x * 256) {
        float4 v = ((float4*)z)[i];
        int c = (i / 1600) & 63;
        float a = a_s[c], b = b_s[c];
        v.x = fmaxf(fmaf(v.x, a, b), 0.f);
        v.y = fmaxf(fmaf(v.y, a, b), 0.f);
        v.z = fmaxf(fmaf(v.z, a, b), 0.f);
        v.w = fmaxf(fmaf(v.w, a, b), 0.f);
        ((float4*)z)[i] = v;
    }
}

// ---------------- Kernel 3b: bf16 z -> normalized fp32 out ------------------
__global__ __launch_bounds__(256) void k_norm_bf(const unsigned short* __restrict__ zbf,
                                                 float* __restrict__ out,
                                                 const float* __restrict__ sc)
{
    __shared__ float a_s[64], b_s[64];
    if (threadIdx.x < 64) { a_s[threadIdx.x] = sc[threadIdx.x]; b_s[threadIdx.x] = sc[64 + threadIdx.x]; }
    __syncthreads();
    const int total8 = ZELEMS / 8;
    for (int i = blockIdx.x * 256 + threadIdx.x; i < total8; i += gridDim.x * 256) {
        short8 v = *(const short8*)&zbf[(size_t)i * 8];
        int c = (i / 800) & 63;
        float a = a_s[c], b = b_s[c];
        float4 o0, o1;
        o0.x = fmaxf(fmaf(bf2f(v[0]), a, b), 0.f);
        o0.y = fmaxf(fmaf(bf2f(v[1]), a, b), 0.f);
        o0.z = fmaxf(fmaf(bf2f(v[2]), a, b), 0.f);
        o0.w = fmaxf(fmaf(bf2f(v[3]), a, b), 0.f);
        o1.x = fmaxf(fmaf(bf2f(v[4]), a, b), 0.f);
        o1.y = fmaxf(fmaf(bf2f(v[5]), a, b), 0.f);
        o1.z = fmaxf(fmaf(bf2f(v[6]), a, b), 0.f);
        o1.w = fmaxf(fmaf(bf2f(v[7]), a, b), 0.f);
        ((float4*)out)[(size_t)i * 2]     = o0;
        ((float4*)out)[(size_t)i * 2 + 1] = o1;
    }
}

extern "C" void kernel_launch(void* const* d_in, const int* in_sizes, int n_in,
                              void* d_out, int out_size, void* d_ws, size_t ws_size,
                              hipStream_t stream)
{
    const float* x     = (const float*)d_in[0];
    const float* Wc    = (const float*)d_in[1];
    const float* bc    = (const float*)d_in[2];
    const float* A     = (const float*)d_in[3];
    const float* gamma = (const float*)d_in[4];
    const float* beta  = (const float*)d_in[5];

    float* out = (float*)d_out;
    const size_t part_bytes = (size_t)(2 * 64 * NBLK) * sizeof(float);        // 2 MB
    const size_t need_bf16  = (size_t)ZELEMS * 2 + part_bytes + 512;          // ~54.5 MB
    const size_t need_f32   = part_bytes + 512;                               // ~2.1 MB

    if (ws_size >= need_bf16) {
        unsigned short* zbf = (unsigned short*)d_ws;
        float* part = (float*)((char*)d_ws + (size_t)ZELEMS * 2);
        float* sc   = part + 2 * 64 * NBLK;
        k_conv_adj<1><<<NBLK, 256, 0, stream>>>(x, Wc, bc, A, nullptr, zbf, part);
        k_reduce<<<64, 256, 0, stream>>>(part, gamma, beta, sc);
        k_norm_bf<<<2048, 256, 0, stream>>>(zbf, out, sc);
    } else if (ws_size >= need_f32) {
        float* part = (float*)d_ws;
        float* sc   = part + 2 * 64 * NBLK;
        k_conv_adj<0><<<NBLK, 256, 0, stream>>>(x, Wc, bc, A, out, nullptr, part);
        k_reduce<<<64, 256, 0, stream>>>(part, gamma, beta, sc);
        k_norm<<<2048, 256, 0, stream>>>(out, sc);
    } else {
        float* part = (float*)d_ws;
        float* sc   = part + 2048;
        k_conv_adj<0><<<NBLK, 256, 0, stream>>>(x, Wc, bc, A, out, nullptr, nullptr);
        k_stats<<<1024, 256, 0, stream>>>(out, part);
        k_bnparams<<<1, 64, 0, stream>>>(part, gamma, beta, sc);
        k_norm<<<2048, 256, 0, stream>>>(out, sc);
    }
}

// Round 5
// 104.893 us; speedup vs baseline: 4.8830x; 1.1890x over previous
//
#include <hip/hip_runtime.h>
#include <stdint.h>

// Problem constants
#define NN     64
#define CIN    64
#define TDIM   256
#define VV     25
#define KA     3
#define NT7    7        // 7 n-tiles of 16 cover 112 padded spatial positions
#define NTILES 4096     // NN * (TDIM/4) t-tiles of 4
#define TPB    4        // tiles per block
#define NBLKS  (NTILES/TPB)   // 1024
#define ZELEMS 26214400 // 64*64*256*25

typedef __attribute__((ext_vector_type(8))) short bf16x8;
typedef __attribute__((ext_vector_type(8))) short short8;
typedef __attribute__((ext_vector_type(4))) float f32x4;
typedef __attribute__((ext_vector_type(4))) short short4v;

__device__ __forceinline__ short f2bf(float f) {
    uint32_t u = __builtin_bit_cast(uint32_t, f);
    u += 0x7fffu + ((u >> 16) & 1u);   // round-to-nearest-even
    return (short)(u >> 16);
}
__device__ __forceinline__ float bf2f(short s) {
    uint32_t u = ((uint32_t)(uint16_t)s) << 16;
    return __builtin_bit_cast(float, u);
}

// stage helpers: 1600 items (ci-quad q, spatial sl); item -> 4 floats of x
__device__ __forceinline__ void stage_loads(const float* __restrict__ xb, int tid,
                                            float xr[7][4]) {
#pragma unroll
    for (int j = 0; j < 7; ++j) {
        int i = tid + j * 256;
        if (i < 1600) {                      // wave-uniform (only wave 0 runs j=6)
            int q = i / 100, sl = i - q * 100;
            const float* p = xb + (size_t)(q * 4) * 6400 + sl;
            xr[j][0] = p[0];
            xr[j][1] = p[6400];
            xr[j][2] = p[12800];
            xr[j][3] = p[19200];
        }
    }
}
__device__ __forceinline__ void stage_write(short* dst, int tid, const float xr[7][4]) {
#pragma unroll
    for (int j = 0; j < 7; ++j) {
        int i = tid + j * 256;
        if (i < 1600) {
            int q = i / 100, sl = i - q * 100;
            int ks = q >> 3, lhi = (q >> 1) & 3, half = q & 1;
            int ntile = sl >> 4, lane2 = (sl & 15) | (lhi << 4);
            short4v v;
            v[0] = f2bf(xr[j][0]);
            v[1] = f2bf(xr[j][1]);
            v[2] = f2bf(xr[j][2]);
            v[3] = f2bf(xr[j][3]);
            *(short4v*)&dst[(((ntile * 2 + ks) * 64 + lane2) << 3) + half * 4] = v;
        }
    }
}

// ---------------- Kernel 1: persistent 4-tile blocks, bf16 MFMA conv+adj ----
// Per block: hoist At (LDS) + W-frags/bias (regs) once; per tile: prefetch
// next x tile into regs during compute, 1 barrier/tile. k-loop is barrier-free
// (y-exchange between conv and adjacency is intra-wave).
template<int MODE>   // 0: fp32 z out, 1: bf16 z out (stats on rounded values)
__global__ __launch_bounds__(256, 2) void k_conv_adj(
    const float* __restrict__ x, const float* __restrict__ Wc,
    const float* __restrict__ bc, const float* __restrict__ A,
    float* __restrict__ zout, unsigned short* __restrict__ zbf,
    float* __restrict__ part)
{
    __shared__ __align__(16) short xbf[2][7168];   // 28.7 KB double-buffered x frags
    __shared__ __align__(16) short y2s[4 * 2688];  // 21.5 KB per-wave y regions
    __shared__ __align__(16) short Ats[3840];      // 7.7 KB A^T bf16 B-frags

    const int tid  = threadIdx.x;
    const int lane = tid & 63;
    const int wid  = tid >> 6;
    const int cl   = lane & 15;
    const int g    = lane >> 4;

    const int tile0 = blockIdx.x * TPB;
    const int n     = tile0 >> 6;       // TPB divides 64 -> same n for all tiles
    const int tt0   = tile0 & 63;
    const float* xslice = x + (size_t)n * CIN * TDIM * VV;

    // ---- At staging (once): Ats[k][w(pad32)][v(stride40)], zero-padded ----
    for (int i = tid; i < 3 * 32 * 40; i += 256) {
        int k3 = i / 1280, r = i - k3 * 1280;
        int w = r / 40, v = r - w * 40;
        float a = (w < VV && v < VV) ? A[(k3 * VV + v) * VV + w] : 0.f;
        Ats[i] = f2bf(a);
    }

    // ---- hoist conv W A-frags + bias into registers (constant per wave) ----
    const int arow = wid * 16 + cl;
    const int klo  = g * 8;
    bf16x8 aW[KA][2];
    float4 b4[KA];
#pragma unroll
    for (int k = 0; k < KA; ++k) {
#pragma unroll
        for (int ks = 0; ks < 2; ++ks) {
            const float* wp = Wc + (size_t)(k * 64 + arow) * CIN + ks * 32 + klo;
            float4 w0 = *(const float4*)wp;
            float4 w1 = *(const float4*)(wp + 4);
            bf16x8 a;
            a[0] = f2bf(w0.x); a[1] = f2bf(w0.y); a[2] = f2bf(w0.z); a[3] = f2bf(w0.w);
            a[4] = f2bf(w1.x); a[5] = f2bf(w1.y); a[6] = f2bf(w1.z); a[7] = f2bf(w1.w);
            aW[k][ks] = a;
        }
        b4[k] = *(const float4*)&bc[k * 64 + wid * 16 + g * 4];
    }

    // ---- zero own y2 region's v-pad columns (wave-local, done once) ----
    const int ybase = wid * 2688;
    for (int i = lane; i < 448; i += 64) {
        int m = i / 7, v = 25 + (i - m * 7);
        y2s[ybase + m * 40 + ((m >> 4) << 3) + v] = 0;
    }

    // ---- stage tile 0 ----
    {
        float xr0[7][4];
        stage_loads(xslice + tt0 * 100, tid, xr0);
        stage_write(xbf[0], tid, xr0);
    }
    __syncthreads();

    float*          zb   = (MODE == 0) ? zout + (size_t)n * 64 * TDIM * VV : nullptr;
    unsigned short* zb16 = (MODE == 1) ? zbf  + (size_t)n * 64 * TDIM * VV : nullptr;

    int cur = 0;
    for (int it = 0; it < TPB; ++it) {
        const int tt = tt0 + it;

        // ---- prefetch next tile's x into regs (hides under compute) ----
        float xr[7][4];
        if (it + 1 < TPB)
            stage_loads(xslice + (tt + 1) * 100, tid, xr);

        // ---- preload conv B-frags from xbf[cur] ----
        bf16x8 bx[NT7][2];
#pragma unroll
        for (int nt = 0; nt < NT7; ++nt)
#pragma unroll
            for (int ks = 0; ks < 2; ++ks)
                bx[nt][ks] = *(const bf16x8*)&xbf[cur][((nt * 2 + ks) * 64 + lane) << 3];

        f32x4 zacc[4][2];
#pragma unroll
        for (int mt = 0; mt < 4; ++mt)
#pragma unroll
            for (int ntw = 0; ntw < 2; ++ntw)
                zacc[mt][ntw] = (f32x4){0.f, 0.f, 0.f, 0.f};

        // ---- k-loop: conv MFMA -> y2 (wave-private) -> adjacency MFMA ----
#pragma unroll
        for (int k = 0; k < KA; ++k) {
#pragma unroll
            for (int nt = 0; nt < NT7; ++nt) {
                f32x4 acc = {b4[k].x, b4[k].y, b4[k].z, b4[k].w};
                acc = __builtin_amdgcn_mfma_f32_16x16x32_bf16(aW[k][0], bx[nt][0], acc, 0, 0, 0);
                acc = __builtin_amdgcn_mfma_f32_16x16x32_bf16(aW[k][1], bx[nt][1], acc, 0, 0, 0);
                int s = nt * 16 + cl;
                if (s < 100) {
                    int tl = s / 25, v = s - tl * 25;
                    int base = ybase + (g * 16 + tl) * 40 + g * 8 + v;
#pragma unroll
                    for (int r = 0; r < 4; ++r)
                        y2s[base + r * 160] = f2bf(acc[r]);
                }
            }
            bf16x8 atf0 = *(const bf16x8*)&Ats[(k * 32 + cl) * 40 + g * 8];
            bf16x8 atf1 = *(const bf16x8*)&Ats[(k * 32 + 16 + cl) * 40 + g * 8];
#pragma unroll
            for (int mt = 0; mt < 4; ++mt) {
                bf16x8 yf = *(const bf16x8*)&y2s[ybase + (mt * 16 + cl) * 40 + mt * 8 + g * 8];
                zacc[mt][0] = __builtin_amdgcn_mfma_f32_16x16x32_bf16(yf, atf0, zacc[mt][0], 0, 0, 0);
                zacc[mt][1] = __builtin_amdgcn_mfma_f32_16x16x32_bf16(yf, atf1, zacc[mt][1], 0, 0, 0);
            }
        }

        // ---- write prefetched x to the other buffer ----
        if (it + 1 < TPB)
            stage_write(xbf[cur ^ 1], tid, xr);

        // ---- epilogue: store z + fused per-channel BN partials ----
        // D: m = wid*64 + mt*16 + g*4 + r -> c = wid*16 + mt*4 + g, tl = r
#pragma unroll
        for (int mt = 0; mt < 4; ++mt) {
            const int c = wid * 16 + mt * 4 + g;
            float s1 = 0.f, s2 = 0.f;
#pragma unroll
            for (int ntw = 0; ntw < 2; ++ntw) {
                int w = ntw * 16 + cl;
#pragma unroll
                for (int r = 0; r < 4; ++r) {
                    float val = zacc[mt][ntw][r];
                    if (MODE == 1) {
                        short b = f2bf(val);
                        val = bf2f(b);          // stats on rounded values
                        if (w < VV)
                            zb16[(size_t)c * 6400 + (tt * 4 + r) * VV + w] = (unsigned short)b;
                    } else {
                        if (w < VV)
                            zb[(size_t)c * 6400 + (tt * 4 + r) * VV + w] = val;
                    }
                    s1 += val; s2 += val * val;   // pad cols are exact 0 -> safe
                }
            }
            s1 += __shfl_xor(s1, 1); s2 += __shfl_xor(s2, 1);
            s1 += __shfl_xor(s1, 2); s2 += __shfl_xor(s2, 2);
            s1 += __shfl_xor(s1, 4); s2 += __shfl_xor(s2, 4);
            s1 += __shfl_xor(s1, 8); s2 += __shfl_xor(s2, 8);
            if (part != nullptr && cl == 0) {
                part[(size_t)c * NTILES + tile0 + it]          = s1;
                part[262144 + (size_t)c * NTILES + tile0 + it] = s2;
            }
        }
        __syncthreads();   // xbf[cur^1] fully staged; xbf[cur] free for re-stage
        cur ^= 1;
    }
}

// ---------------- Kernel 2: reduce partials -> per-channel (a,b) -------------
__global__ __launch_bounds__(256) void k_reduce(
    const float* __restrict__ part, const float* __restrict__ gamma,
    const float* __restrict__ beta, float* __restrict__ sc)
{
    const int c = blockIdx.x;
    const float* p1 = part + (size_t)c * NTILES;
    const float* p2 = part + 262144 + (size_t)c * NTILES;
    float s1 = 0.f, s2 = 0.f;
    for (int i = threadIdx.x; i < NTILES; i += 256) { s1 += p1[i]; s2 += p2[i]; }
#pragma unroll
    for (int o = 1; o < 64; o <<= 1) { s1 += __shfl_xor(s1, o); s2 += __shfl_xor(s2, o); }
    __shared__ float r1[4], r2[4];
    if ((threadIdx.x & 63) == 0) { r1[threadIdx.x >> 6] = s1; r2[threadIdx.x >> 6] = s2; }
    __syncthreads();
    if (threadIdx.x == 0) {
        float t1 = r1[0] + r1[1] + r1[2] + r1[3];
        float t2 = r2[0] + r2[1] + r2[2] + r2[3];
        float mean = t1 * (1.f / 409600.f);
        float var  = t2 * (1.f / 409600.f) - mean * mean;
        float a = gamma[c] * rsqrtf(var + 1e-5f);
        sc[c]      = a;
        sc[64 + c] = beta[c] - mean * a;
    }
}

// ---------------- Fallback stats path (tiny ws): re-read fp32 z -------------
__global__ __launch_bounds__(256) void k_stats(const float* __restrict__ z,
                                               float* __restrict__ part)
{
    const int c = blockIdx.x & 63;
    const int gg = blockIdx.x >> 6;
    float s1 = 0.f, s2 = 0.f;
    for (int nn = 0; nn < 4; ++nn) {
        const float4* row = (const float4*)(z + (size_t)((gg * 4 + nn) * 64 + c) * (TDIM * VV));
        for (int j = threadIdx.x; j < (TDIM * VV) / 4; j += 256) {
            float4 v = row[j];
            s1 += v.x + v.y + v.z + v.w;
            s2 += v.x * v.x + v.y * v.y + v.z * v.z + v.w * v.w;
        }
    }
#pragma unroll
    for (int o = 1; o < 64; o <<= 1) { s1 += __shfl_xor(s1, o); s2 += __shfl_xor(s2, o); }
    __shared__ float r1[4], r2[4];
    if ((threadIdx.x & 63) == 0) { r1[threadIdx.x >> 6] = s1; r2[threadIdx.x >> 6] = s2; }
    __syncthreads();
    if (threadIdx.x == 0) {
        part[blockIdx.x]        = r1[0] + r1[1] + r1[2] + r1[3];
        part[1024 + blockIdx.x] = r2[0] + r2[1] + r2[2] + r2[3];
    }
}

__global__ void k_bnparams(const float* __restrict__ part, const float* __restrict__ gamma,
                           const float* __restrict__ beta, float* __restrict__ sc)
{
    int c = threadIdx.x;
    float s1 = 0.f, s2 = 0.f;
    for (int gg = 0; gg < 16; ++gg) { s1 += part[gg * 64 + c]; s2 += part[1024 + gg * 64 + c]; }
    float mean = s1 * (1.f / 409600.f);
    float var  = s2 * (1.f / 409600.f) - mean * mean;
    float a = gamma[c] * rsqrtf(var + 1e-5f);
    sc[c]      = a;
    sc[64 + c] = beta[c] - mean * a;
}

// ---------------- Kernel 3a: in-place fp32 normalize + affine + ReLU --------
__global__ __launch_bounds__(256) void k_norm(float* __restrict__ z,
                                              const float* __restrict__ sc)
{
    __shared__ float a_s[64], b_s[64];
    if (threadIdx.x < 64) { a_s[threadIdx.x] = sc[threadIdx.x]; b_s[threadIdx.x] = sc[64 + threadIdx.x]; }
    __syncthreads();
    const int total4 = ZELEMS / 4;
    for (int i = blockIdx.x * 256 + threadIdx.x; i < total4; i += gridDim.x * 256) {
        float4 v = ((float4*)z)[i];
        int c = (i / 1600) & 63;
        float a = a_s[c], b = b_s[c];
        v.x = fmaxf(fmaf(v.x, a, b), 0.f);
        v.y = fmaxf(fmaf(v.y, a, b), 0.f);
        v.z = fmaxf(fmaf(v.z, a, b), 0.f);
        v.w = fmaxf(fmaf(v.w, a, b), 0.f);
        ((float4*)z)[i] = v;
    }
}

// ---------------- Kernel 3b: bf16 z -> normalized fp32 out ------------------
__global__ __launch_bounds__(256) void k_norm_bf(const unsigned short* __restrict__ zbf,
                                                 float* __restrict__ out,
                                                 const float* __restrict__ sc)
{
    __shared__ float a_s[64], b_s[64];
    if (threadIdx.x < 64) { a_s[threadIdx.x] = sc[threadIdx.x]; b_s[threadIdx.x] = sc[64 + threadIdx.x]; }
    __syncthreads();
    const int total8 = ZELEMS / 8;
    for (int i = blockIdx.x * 256 + threadIdx.x; i < total8; i += gridDim.x * 256) {
        short8 v = *(const short8*)&zbf[(size_t)i * 8];
        int c = (i / 800) & 63;
        float a = a_s[c], b = b_s[c];
        float4 o0, o1;
        o0.x = fmaxf(fmaf(bf2f(v[0]), a, b), 0.f);
        o0.y = fmaxf(fmaf(bf2f(v[1]), a, b), 0.f);
        o0.z = fmaxf(fmaf(bf2f(v[2]), a, b), 0.f);
        o0.w = fmaxf(fmaf(bf2f(v[3]), a, b), 0.f);
        o1.x = fmaxf(fmaf(bf2f(v[4]), a, b), 0.f);
        o1.y = fmaxf(fmaf(bf2f(v[5]), a, b), 0.f);
        o1.z = fmaxf(fmaf(bf2f(v[6]), a, b), 0.f);
        o1.w = fmaxf(fmaf(bf2f(v[7]), a, b), 0.f);
        ((float4*)out)[(size_t)i * 2]     = o0;
        ((float4*)out)[(size_t)i * 2 + 1] = o1;
    }
}

extern "C" void kernel_launch(void* const* d_in, const int* in_sizes, int n_in,
                              void* d_out, int out_size, void* d_ws, size_t ws_size,
                              hipStream_t stream)
{
    const float* x     = (const float*)d_in[0];
    const float* Wc    = (const float*)d_in[1];
    const float* bc    = (const float*)d_in[2];
    const float* A     = (const float*)d_in[3];
    const float* gamma = (const float*)d_in[4];
    const float* beta  = (const float*)d_in[5];

    float* out = (float*)d_out;
    const size_t part_bytes = (size_t)(2 * 64 * NTILES) * sizeof(float);      // 2 MB
    const size_t need_bf16  = (size_t)ZELEMS * 2 + part_bytes + 512;          // ~54.5 MB
    const size_t need_f32   = part_bytes + 512;                               // ~2.1 MB

    if (ws_size >= need_bf16) {
        unsigned short* zbf = (unsigned short*)d_ws;
        float* part = (float*)((char*)d_ws + (size_t)ZELEMS * 2);
        float* sc   = part + 2 * 64 * NTILES;
        k_conv_adj<1><<<NBLKS, 256, 0, stream>>>(x, Wc, bc, A, nullptr, zbf, part);
        k_reduce<<<64, 256, 0, stream>>>(part, gamma, beta, sc);
        k_norm_bf<<<2048, 256, 0, stream>>>(zbf, out, sc);
    } else if (ws_size >= need_f32) {
        float* part = (float*)d_ws;
        float* sc   = part + 2 * 64 * NTILES;
        k_conv_adj<0><<<NBLKS, 256, 0, stream>>>(x, Wc, bc, A, out, nullptr, part);
        k_reduce<<<64, 256, 0, stream>>>(part, gamma, beta, sc);
        k_norm<<<2048, 256, 0, stream>>>(out, sc);
    } else {
        float* part = (float*)d_ws;
        float* sc   = part + 2048;
        k_conv_adj<0><<<NBLKS, 256, 0, stream>>>(x, Wc, bc, A, out, nullptr, nullptr);
        k_stats<<<1024, 256, 0, stream>>>(out, part);
        k_bnparams<<<1, 64, 0, stream>>>(part, gamma, beta, sc);
        k_norm<<<2048, 256, 0, stream>>>(out, sc);
    }
}